// Round 12
// baseline (911.082 us; speedup 1.0000x reference)
//
#include <hip/hip_runtime.h>
#include <math.h>

#define NN 128
#define SM 129   // padded LDS stride for 128-wide f32 tiles
#define RS 132   // row-panel stride (doubles)
#define SS 17    // per-wave scratch stride (doubles)
#define SF 132   // f32 staging stride (16B-aligned rows -> float4)
#define XT 136   // kz transposed-X stride (4-way write conflict, 16B-aligned)
#define ZS 132   // kzs staged-matrix stride

typedef double d4 __attribute__((ext_vector_type(4)));

// ---------------------------------------------------------------------------
// K1 (R17): build symmetric-normalized Laplacian per graph (f32) only.
// ---------------------------------------------------------------------------
__global__ __launch_bounds__(256) void k1_lap(
    const int* __restrict__ src, const int* __restrict__ dst,
    int E, float* __restrict__ Lout) {
  extern __shared__ float sm1[];            // A[128*129] + dinv[128]
  float* A    = sm1;
  float* dinv = sm1 + NN * SM;
  const int g   = blockIdx.x;
  const int tid = threadIdx.x;

  for (int e = tid; e < NN * NN; e += 256) {
    int i = e >> 7, j = e & 127;
    A[i * SM + j] = 0.f;
  }
  __syncthreads();
  const int* s = src + (size_t)g * E;
  const int* d = dst + (size_t)g * E;
  for (int e = tid; e < E; e += 256) {
    int a = s[e], b = d[e];
    A[a * SM + b] = 1.f;     // benign races: all write 1.0
    A[b * SM + a] = 1.f;
  }
  __syncthreads();
  if (tid < NN) {
    float acc = 0.f;
    for (int j = 0; j < NN; ++j) acc += A[tid * SM + j];
    dinv[tid] = (acc > 0.f) ? (float)(1.0 / sqrt((double)acc)) : 0.f;
  }
  __syncthreads();
  float* Lg = Lout + (size_t)g * NN * NN;
  for (int e = tid; e < NN * NN; e += 256) {
    int i = e >> 7, j = e & 127;
    Lg[e] = ((i == j) ? 1.f : 0.f) - dinv[i] * dinv[j] * A[i * SM + j];
  }
}

// ---------------------------------------------------------------------------
// KPOW2 (R22): L2 = L @ L. 512 blocks. L staged f32 in LDS. 2 blocks/CU.
// ---------------------------------------------------------------------------
__global__ __launch_bounds__(512, 4) void kpow2(
    const float* __restrict__ L, double* __restrict__ L2) {
  extern __shared__ float Bs[];             // 128 x 132 f32
  const int bid = blockIdx.x;
  const int g = bid >> 3, q = bid & 7;
  const int tid = threadIdx.x;
  const int wv = tid >> 6, ln = tid & 63;
  const int m  = ln & 15, kq = ln >> 4;
  const int rb = 16 * q;                    // row-band base
  const int cb = wv;                        // column tile

  int rIdx[4], cIdx[4];
  {
    d4 z = {0.0, 0.0, 0.0, 0.0};
    d4 pr = __builtin_amdgcn_mfma_f64_16x16x4f64((double)m, 1.0, z, 0, 0, 0);
    d4 pc = __builtin_amdgcn_mfma_f64_16x16x4f64(1.0, (double)m, z, 0, 0, 0);
#pragma unroll
    for (int r = 0; r < 4; ++r) {
      rIdx[r] = ((int)(pr[r] * 0.25 + 0.5)) & 15;
      cIdx[r] = ((int)(pc[r] * 0.25 + 0.5)) & 15;
    }
  }

  const float* Lg = L + (size_t)g * NN * NN;
  for (int e4 = tid; e4 < (NN * NN) / 4; e4 += 512) {
    int i = e4 >> 5, j4 = (e4 & 31) * 4;
    *(float4*)(Bs + i * SF + j4) = *(const float4*)(Lg + i * NN + j4);
  }
  __syncthreads();

  d4 acc = {0.0, 0.0, 0.0, 0.0};
  for (int kc = 0; kc < 32; ++kc) {
    double a = (double)Bs[(rb + m) * SF + 4 * kc + kq];
    double b = (double)Bs[(4 * kc + kq) * SF + 16 * cb + m];
    acc = __builtin_amdgcn_mfma_f64_16x16x4f64(a, b, acc, 0, 0, 0);
  }
  double* out = L2 + (size_t)g * NN * NN;
#pragma unroll
  for (int r = 0; r < 4; ++r)
    out[(rb + rIdx[r]) * NN + 16 * cb + cIdx[r]] = acc[r];
}

// ---------------------------------------------------------------------------
// KPOW34 (R22): 512 blocks = g(6b) x quarter(2b) x job(1b).
// ---------------------------------------------------------------------------
__global__ __launch_bounds__(512, 4) void kpow34(
    const float* __restrict__ L, const double* __restrict__ L2,
    double* __restrict__ L3, double* __restrict__ L4) {
  extern __shared__ float Bs[];             // 128 x 132 f32 (job0 only)
  const int bid = blockIdx.x;
  const int g = bid >> 3, q = (bid >> 1) & 3, job = bid & 1;
  const int tid = threadIdx.x;
  const int wv = tid >> 6, ln = tid & 63;
  const int m  = ln & 15, kq = ln >> 4;
  const int rb = 32 * q + 16 * (wv & 1);
  const int cb0 = 2 * (wv >> 1);

  int rIdx[4], cIdx[4];
  {
    d4 z = {0.0, 0.0, 0.0, 0.0};
    d4 pr = __builtin_amdgcn_mfma_f64_16x16x4f64((double)m, 1.0, z, 0, 0, 0);
    d4 pc = __builtin_amdgcn_mfma_f64_16x16x4f64(1.0, (double)m, z, 0, 0, 0);
#pragma unroll
    for (int r = 0; r < 4; ++r) {
      rIdx[r] = ((int)(pr[r] * 0.25 + 0.5)) & 15;
      cIdx[r] = ((int)(pc[r] * 0.25 + 0.5)) & 15;
    }
  }

  const float*  Lg  = L  + (size_t)g * NN * NN;
  const double* L2g = L2 + (size_t)g * NN * NN;
  if (job == 0) {
    for (int e4 = tid; e4 < (NN * NN) / 4; e4 += 512) {
      int i = e4 >> 5, j4 = (e4 & 31) * 4;
      *(float4*)(Bs + i * SF + j4) = *(const float4*)(Lg + i * NN + j4);
    }
  }
  __syncthreads();

  d4 acc[2];
#pragma unroll
  for (int c = 0; c < 2; ++c) {
    acc[c][0] = 0.0; acc[c][1] = 0.0; acc[c][2] = 0.0; acc[c][3] = 0.0;
  }
  if (job == 0) {
    for (int kc = 0; kc < 32; ++kc) {
      double a = L2g[(rb + m) * NN + 4 * kc + kq];
#pragma unroll
      for (int c = 0; c < 2; ++c) {
        double b = (double)Bs[(4 * kc + kq) * SF + 16 * (cb0 + c) + m];
        acc[c] = __builtin_amdgcn_mfma_f64_16x16x4f64(a, b, acc[c], 0, 0, 0);
      }
    }
  } else {
    for (int kc = 0; kc < 32; ++kc) {
      double a = L2g[(rb + m) * NN + 4 * kc + kq];
#pragma unroll
      for (int c = 0; c < 2; ++c) {
        double b = L2g[(4 * kc + kq) * NN + 16 * (cb0 + c) + m];
        acc[c] = __builtin_amdgcn_mfma_f64_16x16x4f64(a, b, acc[c], 0, 0, 0);
      }
    }
  }
  double* out = (job == 0 ? L3 : L4) + (size_t)g * NN * NN;
#pragma unroll
  for (int c = 0; c < 2; ++c)
#pragma unroll
    for (int r = 0; r < 4; ++r)
      out[(rb + rIdx[r]) * NN + 16 * (cb0 + c) + cIdx[r]] = acc[c][r];
}

// ---------------------------------------------------------------------------
// K2 (R14 exact, FROZEN): algebraic assembly + blocked GJ with serial-Pi.
// 268us stable; VGPR 64 + 64 AGPR = full 128 budget at (512,4).
// R18/R19/R21 restructurings ALL spilled to scratch. DO NOT MODIFY.
// ---------------------------------------------------------------------------
__global__ __launch_bounds__(512, 4) void k2_filter(
    const float* __restrict__ L, const double* __restrict__ L2,
    const double* __restrict__ L3, const double* __restrict__ L4,
    const float* __restrict__ C, int NF, float* __restrict__ W) {
  extern __shared__ char smraw[];
  double* Rp  = (double*)smraw;                      // row panel 16x132
  double* Scd = (double*)(smraw + 16 * RS * 8);      // 8 wave scratches 16x17
  double* Pv  = (double*)(smraw + 16 * RS * 8 + 8 * 16 * SS * 8); // Pi 16x17

  const int bid = blockIdx.x;
  const int g = bid / NF, f = bid % NF;
  const int tid = threadIdx.x;
  const int wv = tid >> 6, ln = tid & 63;
  const int m  = ln & 15, kq = ln >> 4;
  double* S = Scd + wv * 16 * SS;

  double csum = 0.0;
  for (int q = 0; q < NF; ++q) { double c = (double)C[q]; csum += c * c; }
  double cn = sqrt(csum); if (cn < 1e-12) cn = 1e-12;
  const double a4 = 6.25e-6;                         // (STEP/2)^4
  const double coef = 1.4142135623730951 * a4 * ((double)C[f] / cn);
  const float  bf = (float)((double)f * 0.1);
  const double bb = (double)bf;
  const double c3 = -4.0 * bb;
  const double c2 = 6.0 * bb * bb;
  const double c1 = -4.0 * bb * bb * bb;
  const double c0 = bb * bb * bb * bb + a4;

  int rIdx[4], cIdx[4];
  {
    d4 z = {0.0, 0.0, 0.0, 0.0};
    d4 pr = __builtin_amdgcn_mfma_f64_16x16x4f64((double)m, 1.0, z, 0, 0, 0);
    d4 pc = __builtin_amdgcn_mfma_f64_16x16x4f64(1.0, (double)m, z, 0, 0, 0);
#pragma unroll
    for (int r = 0; r < 4; ++r) {
      rIdx[r] = ((int)(pr[r] * 0.25 + 0.5)) & 15;
      cIdx[r] = ((int)(pc[r] * 0.25 + 0.5)) & 15;
    }
  }

  // phase A: assemble T (D-layout) from the power matrices -- pure n^2
  const float*  Lg  = L  + (size_t)g * NN * NN;
  const double* L2g = L2 + (size_t)g * NN * NN;
  const double* L3g = L3 + (size_t)g * NN * NN;
  const double* L4g = L4 + (size_t)g * NN * NN;
  d4 T[8];
#pragma unroll
  for (int cb = 0; cb < 8; ++cb)
#pragma unroll
    for (int r = 0; r < 4; ++r) {
      int i = 16 * wv + rIdx[r], j = 16 * cb + cIdx[r];
      int idx = i * NN + j;
      double v = L4g[idx];
      v = fma(c3, L3g[idx], v);
      v = fma(c2, L2g[idx], v);
      v = fma(c1, (double)Lg[idx], v);
      if (i == j) v += c0;
      T[cb][r] = v;
    }

  // phase 4: blocked GJ, 8 steps, 3 block-barriers each, NOT unrolled
#pragma unroll 1
  for (int t = 0; t < 8; ++t) {
    if (wv == t) {
#pragma unroll
      for (int cb = 0; cb < 8; ++cb)
#pragma unroll
        for (int r = 0; r < 4; ++r)
          Rp[rIdx[r] * RS + 16 * cb + cIdx[r]] = T[cb][r];
    }
    __syncthreads();                                 // B1 (Rp visible)

    if (wv == t) {
      double sr[4];
#pragma unroll
      for (int r = 0; r < 4; ++r) sr[r] = Rp[(4 * r + kq) * RS + 16 * t + m];
#pragma unroll
      for (int k = 0; k < 16; ++k) {
        const int kr = k >> 2, kl = k & 3;
        double pv   = __shfl(sr[kr], 16 * kl + k);
        double rowv = __shfl(sr[kr], 16 * kl + m);
        double cv[4];
#pragma unroll
        for (int r = 0; r < 4; ++r) cv[r] = __shfl(sr[r], 16 * kq + k);
        double dp = 1.0 / pv;
#pragma unroll
        for (int r = 0; r < 4; ++r) {
          int i = 4 * r + kq;
          double nv;
          if (i == k)      nv = (m == k) ? dp : rowv * dp;
          else if (m == k) nv = -cv[r] * dp;
          else             nv = fma(-(cv[r] * dp), rowv, sr[r]);
          sr[r] = nv;
        }
      }
#pragma unroll
      for (int r = 0; r < 4; ++r) Pv[(4 * r + kq) * SS + m] = sr[r];
    }
    __syncthreads();                                 // B2 (Pi visible)

#pragma unroll
    for (int cb = 0; cb < 8; ++cb) {
      if (cb != t) continue;
      if (wv == t) {
#pragma unroll
        for (int r = 0; r < 4; ++r) T[cb][r] = Pv[rIdx[r] * SS + cIdx[r]];
      } else {
#pragma unroll
        for (int r = 0; r < 4; ++r) S[rIdx[r] * SS + cIdx[r]] = T[cb][r];
        __builtin_amdgcn_wave_barrier();
        d4 ncv = {0.0, 0.0, 0.0, 0.0};
#pragma unroll
        for (int kc = 0; kc < 4; ++kc) {
          double a = S[m * SS + 4 * kc + kq];
          double b = -Pv[(4 * kc + kq) * SS + m];
          ncv = __builtin_amdgcn_mfma_f64_16x16x4f64(a, b, ncv, 0, 0, 0);
        }
        T[cb] = ncv;
        __builtin_amdgcn_wave_barrier();
#pragma unroll
        for (int r = 0; r < 4; ++r) S[rIdx[r] * SS + cIdx[r]] = T[cb][r];
      }
    }
    __builtin_amdgcn_wave_barrier();

    const double* asrc = (wv == t) ? Pv : S;
#pragma unroll
    for (int cb = 0; cb < 8; ++cb) {
      if (cb == t) continue;
      d4 acc;
      if (wv == t) { acc[0] = 0.0; acc[1] = 0.0; acc[2] = 0.0; acc[3] = 0.0; }
      else         { acc = T[cb]; }
#pragma unroll
      for (int kc = 0; kc < 4; ++kc) {
        double a = asrc[m * SS + 4 * kc + kq];
        double b = Rp[(4 * kc + kq) * RS + 16 * cb + m];
        acc = __builtin_amdgcn_mfma_f64_16x16x4f64(a, b, acc, 0, 0, 0);
      }
      T[cb] = acc;
    }
    __syncthreads();                                 // B3 (Rp/Pv reads done)
  }

  // phase 5: W += coef * K^{-1}
  float* Wg = W + (size_t)g * NN * NN;
#pragma unroll
  for (int cb = 0; cb < 8; ++cb)
#pragma unroll
    for (int r = 0; r < 4; ++r)
      atomicAdd(&Wg[(16 * wv + rIdx[r]) * NN + 16 * cb + cIdx[r]],
                (float)(coef * T[cb][r]));
}

// ---------------------------------------------------------------------------
// KZ (R29): Z = X @ X^T per graph (Z 128x128). Replaces k3's GEMM1+GEMM2
// depth-1152 work: G is later formed as (I-W) Z (I-W)^T (0.54 GFLOP) instead
// of y@y^T via y = (I-W)X (4.8 GFLOP) -- and the 144MB Gp traffic + kgred
// vanish. 512 blocks = g(6b) x 16-row band (3b). X^T chunks staged in LDS
// ([64][136]: 4-way write conflict, reads conflict-free). Thread: 1 row x
// 4 cols; per dl: broadcast a + 1 b128 + 4 FMA (R26-proven pattern).
// ---------------------------------------------------------------------------
__global__ __launch_bounds__(512, 8) void kz(
    const float* __restrict__ x, const float* __restrict__ rs,
    float* __restrict__ Z, int F0, int R, int DTOT, float rscale) {
  extern __shared__ float xt[];             // [64][136]
  const int bid = blockIdx.x;
  const int g = bid >> 3, band = bid & 7;
  const int tid = threadIdx.x;
  const int r = tid >> 5, cg = tid & 31;
  const int i = band * 16 + r;
  const float* xg = x + (size_t)g * NN * F0;
  const float* rg = rs + (size_t)g * NN * R;
  const int chunks = (DTOT + 63) >> 6;

  float acc[4] = {0.f, 0.f, 0.f, 0.f};
  for (int c = 0; c < chunks; ++c) {
    __syncthreads();                        // previous-chunk reads done
    for (int e = tid; e < NN * 64; e += 512) {
      int k = e >> 6, dl = e & 63;
      int d = c * 64 + dl;
      float v = 0.f;
      if (d < DTOT) v = (d < F0) ? xg[k * F0 + d] : rg[k * R + (d - F0)] * rscale;
      xt[dl * XT + k] = v;
    }
    __syncthreads();
    for (int dl = 0; dl < 64; ++dl) {
      float a = xt[dl * XT + i];                              // broadcast
      float4 b = *(const float4*)(xt + dl * XT + 4 * cg);     // b128
      acc[0] = fmaf(a, b.x, acc[0]);
      acc[1] = fmaf(a, b.y, acc[1]);
      acc[2] = fmaf(a, b.z, acc[2]);
      acc[3] = fmaf(a, b.w, acc[3]);
    }
  }
  float4 o = {acc[0], acc[1], acc[2], acc[3]};
  *(float4*)(Z + (size_t)g * NN * NN + i * NN + 4 * cg) = o;
}

// ---------------------------------------------------------------------------
// KZS1 (R29): M = Z - W @ Z. 512 blocks = g x 16-row band. Z (full) and the
// W band both staged in LDS -> pure-LDS k-loop (broadcast a + b128 + 4 FMA).
// ---------------------------------------------------------------------------
__global__ __launch_bounds__(512, 4) void kzs1(
    const float* __restrict__ Z, const float* __restrict__ W,
    float* __restrict__ M) {
  extern __shared__ float smz[];
  float* zb = smz;                          // [128][132]
  float* wb = smz + NN * ZS;                // [16][132]
  const int bid = blockIdx.x;
  const int g = bid >> 3, band = bid & 7;
  const int tid = threadIdx.x;
  const int r = tid >> 5, cg = tid & 31;
  const int i = band * 16 + r;
  const float* Zg = Z + (size_t)g * NN * NN;
  const float* Wg = W + (size_t)g * NN * NN;

  for (int e4 = tid; e4 < NN * 32; e4 += 512) {
    int row = e4 >> 5, c4 = (e4 & 31) * 4;
    *(float4*)(zb + row * ZS + c4) = *(const float4*)(Zg + row * NN + c4);
  }
  {
    int row = tid >> 5, c4 = (tid & 31) * 4;
    *(float4*)(wb + row * ZS + c4) =
        *(const float4*)(Wg + (band * 16 + row) * NN + c4);
  }
  __syncthreads();

  float acc[4] = {0.f, 0.f, 0.f, 0.f};
  for (int k = 0; k < NN; ++k) {
    float a = wb[r * ZS + k];                             // broadcast
    float4 b = *(const float4*)(zb + k * ZS + 4 * cg);    // b128
    acc[0] = fmaf(a, b.x, acc[0]);
    acc[1] = fmaf(a, b.y, acc[1]);
    acc[2] = fmaf(a, b.z, acc[2]);
    acc[3] = fmaf(a, b.w, acc[3]);
  }
  float4 z4 = *(const float4*)(zb + i * ZS + 4 * cg);
  float4 o = {z4.x - acc[0], z4.y - acc[1], z4.z - acc[2], z4.w - acc[3]};
  *(float4*)(M + (size_t)g * NN * NN + i * NN + 4 * cg) = o;
}

// ---------------------------------------------------------------------------
// KZS2 (R29): G = M - M @ W. Same structure; W (full) + M band in LDS.
// ---------------------------------------------------------------------------
__global__ __launch_bounds__(512, 4) void kzs2(
    const float* __restrict__ M, const float* __restrict__ W,
    float* __restrict__ G) {
  extern __shared__ float smz[];
  float* wb = smz;                          // [128][132]
  float* mb = smz + NN * ZS;                // [16][132]
  const int bid = blockIdx.x;
  const int g = bid >> 3, band = bid & 7;
  const int tid = threadIdx.x;
  const int r = tid >> 5, cg = tid & 31;
  const int i = band * 16 + r;
  const float* Mg = M + (size_t)g * NN * NN;
  const float* Wg = W + (size_t)g * NN * NN;

  for (int e4 = tid; e4 < NN * 32; e4 += 512) {
    int row = e4 >> 5, c4 = (e4 & 31) * 4;
    *(float4*)(wb + row * ZS + c4) = *(const float4*)(Wg + row * NN + c4);
  }
  {
    int row = tid >> 5, c4 = (tid & 31) * 4;
    *(float4*)(mb + row * ZS + c4) =
        *(const float4*)(Mg + (band * 16 + row) * NN + c4);
  }
  __syncthreads();

  float acc[4] = {0.f, 0.f, 0.f, 0.f};
  for (int k = 0; k < NN; ++k) {
    float a = mb[r * ZS + k];                             // broadcast
    float4 b = *(const float4*)(wb + k * ZS + 4 * cg);    // b128
    acc[0] = fmaf(a, b.x, acc[0]);
    acc[1] = fmaf(a, b.y, acc[1]);
    acc[2] = fmaf(a, b.z, acc[2]);
    acc[3] = fmaf(a, b.w, acc[3]);
  }
  float4 m4 = *(const float4*)(mb + r * ZS + 4 * cg);
  float4 o = {m4.x - acc[0], m4.y - acc[1], m4.z - acc[2], m4.w - acc[3]};
  *(float4*)(G + (size_t)g * NN * NN + i * NN + 4 * cg) = o;
}

// ---------------------------------------------------------------------------
// KEMB (R29): emb_d = sum_k v_k X[k,d], v_k = (1 - colsum_k(W))/128.
// Exact reassociation of colmean((I-W)X). 256 blocks = g x d-quarter.
// ---------------------------------------------------------------------------
__global__ __launch_bounds__(256) void kemb(
    const float* __restrict__ x, const float* __restrict__ rs,
    const float* __restrict__ W, float* __restrict__ emb,
    int F0, int R, int DTOT, float rscale) {
  __shared__ float v[NN];
  const int bid = blockIdx.x;
  const int g = bid >> 2, q = bid & 3;
  const int tid = threadIdx.x;
  const float* Wg = W + (size_t)g * NN * NN;
  if (tid < NN) {
    float s = 0.f;
    for (int i2 = 0; i2 < NN; ++i2) s += Wg[i2 * NN + tid];   // coalesced
    v[tid] = (1.f - s) * (1.f / 128.f);
  }
  __syncthreads();
  const float* xg = x + (size_t)g * NN * F0;
  const float* rg = rs + (size_t)g * NN * R;
  const int DQ = (DTOT + 3) >> 2;
  for (int dd = tid; dd < DQ; dd += 256) {
    int d = q * DQ + dd;
    if (d < DTOT) {
      float acc = 0.f;
      for (int k = 0; k < NN; ++k) {
        float xv = (d < F0) ? xg[k * F0 + d] : rg[k * R + (d - F0)] * rscale;
        acc = fmaf(v[k], xv, acc);
      }
      emb[(size_t)g * 1152 + d] = acc;
    }
  }
}

// ---------------------------------------------------------------------------
// K45 (R28): full-machine parallelism for both phases.
// Blocks 0..255 = k4 partials (4/graph, 32-row quarter; f64 atomicAdd into
// spt[g], scaling -> k5b). Blocks 256..383 = k5a cdist (2/row).
// ---------------------------------------------------------------------------
__global__ __launch_bounds__(256) void k45_fused(
    const float* __restrict__ G, double* __restrict__ spt,
    const float* __restrict__ emb, float* __restrict__ Dm, int DTOT) {
  __shared__ float inr[NN];
  __shared__ double red[4];
  const int bid = blockIdx.x, tid = threadIdx.x;
  if (bid < 256) {
    const int g = bid >> 2, qt = bid & 3;
    const float* Gg = G + (size_t)g * NN * NN;
    if (tid < NN) {
      float n = sqrtf(fmaxf(Gg[tid * NN + tid], 0.f));
      inr[tid] = 1.f / fmaxf(n, 1e-12f);
    }
    __syncthreads();
    double s = 0.0;
    const int base = qt * 4096;                 // 32-row quarter
    for (int e0 = tid; e0 < 4096; e0 += 256) {
      int e = base + e0;
      int i = e >> 7, j = e & 127;
      s += (double)(fabsf(Gg[e]) * inr[i] * inr[j]);
    }
    for (int off = 32; off; off >>= 1) s += __shfl_down(s, off);
    int wave = tid >> 6, lane = tid & 63;
    if (lane == 0) red[wave] = s;
    __syncthreads();
    if (tid == 0) atomicAdd(&spt[g], red[0] + red[1] + red[2] + red[3]);
  } else {
    const int ii = bid - 256;
    const int i = ii >> 1, h = ii & 1;          // row i, j-half h
    const int wv = tid >> 6, l = tid & 63;
    float ei[18];
#pragma unroll
    for (int s = 0; s < 18; ++s) {
      int d = l + 64 * s;
      ei[s] = (d < DTOT) ? emb[(size_t)i * 1152 + d] : 0.f;
    }
    for (int jj = 8 * h; jj < 8 * h + 8; ++jj) {
      int j = 4 * jj + wv;
      float acc = 0.f;
#pragma unroll
      for (int s = 0; s < 18; ++s) {
        int d = l + 64 * s;
        if (d < DTOT) {
          float df = ei[s] - emb[(size_t)j * 1152 + d];
          acc = fmaf(df, df, acc);
        }
      }
      for (int off = 32; off; off >>= 1) acc += __shfl_down(acc, off);
      if (l == 0) Dm[i * 64 + j] = (acc > 0.f) ? sqrtf(acc) : 0.f;
    }
  }
}

// ---------------------------------------------------------------------------
// K5b (R28): 4 waves, one class per wave; spt holds raw |.|-sum (scaled here).
// ---------------------------------------------------------------------------
__global__ __launch_bounds__(256) void k5b_final(
    const float* __restrict__ Dm, const double* __restrict__ spt,
    const float* __restrict__ C, int NF,
    const int* __restrict__ ncls, float* __restrict__ out) {
  __shared__ double redH[8];     // per-wave {hl1, hl2}
  __shared__ double redS;
  const int tid = threadIdx.x;
  const int wv = tid >> 6, lane = tid & 63;
  const int nc = ncls[0];

  double hl1 = 0.0, hl2 = 0.0;
  const double beta = 1.0 / (double)nc + 1e-13;
  for (int cc = wv; cc < nc; cc += 4) {
    bool ip = (lane % nc) == cc;
    double ps = 0.0, ns = 0.0;
    for (int j = 0; j < 64; ++j) {
      double dv = (double)Dm[lane * 64 + j];
      bool jp = (j % nc) == cc;
      if (ip && jp) ps += dv;
      if (!ip && !jp) ns += dv;
    }
    for (int off = 32; off; off >>= 1) {
      ps += __shfl_down(ps, off);
      ns += __shfl_down(ns, off);
    }
    if (lane == 0) {
      int npos = 0;
      for (int q = 0; q < 64; ++q) if (q % nc == cc) npos++;
      int nneg = 64 - npos;
      hl2 += ps / ((double)npos * (double)npos);
      hl1 += -(ns / ((double)nneg * (double)nneg)) / beta;
    }
  }
  if (lane == 0) { redH[2 * wv] = hl1; redH[2 * wv + 1] = hl2; }

  if (wv == 0) {
    double sp = -spt[lane] * (1.0 / (double)(NN * NN));   // k4 scaling
    double spf = sp * exp(-((double)(64 - lane)) * log(64.0));
    for (int off = 32; off; off >>= 1) spf += __shfl_down(spf, off);
    if (lane == 0) redS = spf;
  }
  __syncthreads();

  if (tid == 0) {
    double h1 = redH[0] + redH[2] + redH[4] + redH[6];
    double h2 = redH[1] + redH[3] + redH[5] + redH[7];
    double l1 = 0.0, l2 = 0.0;
    for (int q = 0; q < NF; ++q) { double cv = (double)C[q]; l1 += fabs(cv); l2 += cv * cv; }
    l2 = sqrt(l2); if (l2 < 1e-12) l2 = 1e-12;
    double dims = sqrt((double)NF);
    double sc = (dims - l1 / l2) / (dims - 1.0);
    out[0] = (float)(sc + h2 + h1 + redS);
  }
}

// ---------------------------------------------------------------------------
extern "C" void kernel_launch(void* const* d_in, const int* in_sizes, int n_in,
                              void* d_out, int out_size, void* d_ws, size_t ws_size,
                              hipStream_t stream) {
  (void)n_in; (void)out_size; (void)ws_size;
  const float* x    = (const float*)d_in[0];
  const float* rs   = (const float*)d_in[1];
  const float* C    = (const float*)d_in[2];
  const int*   esrc = (const int*)d_in[3];
  const int*   edst = (const int*)d_in[4];
  const int*   ncls = (const int*)d_in[5];
  float* out = (float*)d_out;

  const int F0   = in_sizes[0] / (64 * 128);
  const int R    = in_sizes[1] / (64 * 128);
  const int NF   = in_sizes[2];
  const int E    = in_sizes[3] / 64;
  const int DTOT = F0 + R;
  const float rscale = (float)(1.0 / sqrt((double)R));

  char* ws = (char*)d_ws;
  size_t off = 0;
  float*  L    = (float*)(ws + off);  off += (size_t)64 * NN * NN * 4;   // 4MB; reused as dense G
  float*  W    = (float*)(ws + off);  off += (size_t)64 * NN * NN * 4;   // 4MB
  double* L2d  = (double*)(ws + off); off += (size_t)64 * NN * NN * 8;   // 8MB; Z overlays (dead after k2)
  double* L3d  = (double*)(ws + off); off += (size_t)64 * NN * NN * 8;   // 8MB; M overlays
  double* L4d  = (double*)(ws + off); off += (size_t)64 * NN * NN * 8;   // 8MB
  float*  emb  = (float*)(ws + off);  off += (size_t)64 * 1152 * 4;
  double* spt  = (double*)(ws + off); off += (size_t)64 * 8;
  float*  Dm   = (float*)(ws + off);  off += (size_t)64 * 64 * 4;
  float*  Z    = (float*)L2d;         // 4MB, after k2
  float*  M    = (float*)L3d;         // 4MB, after k2
  float*  G    = L;                   // dense G reuses L (dead after k2)

  hipMemsetAsync(W, 0, (size_t)64 * NN * NN * 4, stream);
  hipMemsetAsync(spt, 0, (size_t)64 * 8, stream);   // k4 partials accumulate

  const int lds1 = (NN * SM + NN) * 4;             // 66560
  const int ldsf = NN * SF * 4;                    // 67584 (f32 staging)
  const int lds2 = 16 * RS * 8 + 8 * 16 * SS * 8 + 16 * SS * 8;  // 36480
  const int ldsz  = 64 * XT * 4;                   // 34816 (kz)
  const int ldszs = (NN * ZS + 16 * ZS) * 4;       // 76032 (kzs1/2) -> 2/CU
  hipFuncSetAttribute((const void*)k1_lap,    hipFuncAttributeMaxDynamicSharedMemorySize, lds1);
  hipFuncSetAttribute((const void*)kpow2,     hipFuncAttributeMaxDynamicSharedMemorySize, ldsf);
  hipFuncSetAttribute((const void*)kpow34,    hipFuncAttributeMaxDynamicSharedMemorySize, ldsf);
  hipFuncSetAttribute((const void*)k2_filter, hipFuncAttributeMaxDynamicSharedMemorySize, lds2);
  hipFuncSetAttribute((const void*)kz,        hipFuncAttributeMaxDynamicSharedMemorySize, ldsz);
  hipFuncSetAttribute((const void*)kzs1,      hipFuncAttributeMaxDynamicSharedMemorySize, ldszs);
  hipFuncSetAttribute((const void*)kzs2,      hipFuncAttributeMaxDynamicSharedMemorySize, ldszs);

  k1_lap<<<64, 256, lds1, stream>>>(esrc, edst, E, L);
  kpow2<<<512, 512, ldsf, stream>>>(L, L2d);
  kpow34<<<512, 512, ldsf, stream>>>(L, L2d, L3d, L4d);
  k2_filter<<<64 * NF, 512, lds2, stream>>>(L, L2d, L3d, L4d, C, NF, W);
  kz<<<512, 512, ldsz, stream>>>(x, rs, Z, F0, R, DTOT, rscale);
  kzs1<<<512, 512, ldszs, stream>>>(Z, W, M);
  kzs2<<<512, 512, ldszs, stream>>>(M, W, G);
  kemb<<<256, 256, 0, stream>>>(x, rs, W, emb, F0, R, DTOT, rscale);
  k45_fused<<<384, 256, 0, stream>>>(G, spt, emb, Dm, DTOT);
  k5b_final<<<1, 256, 0, stream>>>(Dm, spt, C, NF, ncls, out);
}

// Round 13
// 635.594 us; speedup vs baseline: 1.4334x; 1.4334x over previous
//
#include <hip/hip_runtime.h>
#include <math.h>

#define NN 128
#define SM 129   // padded LDS stride for 128-wide f32 tiles
#define RS 132   // row-panel stride (doubles)
#define SS 17    // per-wave scratch stride (doubles)
#define SF 132   // f32 staging stride (16B-aligned rows -> float4)
#define CS 132   // kz transposed-chunk stride (floats)
#define ZS 132   // kzs staged-matrix stride (floats)

typedef double d4 __attribute__((ext_vector_type(4)));

// ---------------------------------------------------------------------------
// K1 (R17): build symmetric-normalized Laplacian per graph (f32) only.
// ---------------------------------------------------------------------------
__global__ __launch_bounds__(256) void k1_lap(
    const int* __restrict__ src, const int* __restrict__ dst,
    int E, float* __restrict__ Lout) {
  extern __shared__ float sm1[];            // A[128*129] + dinv[128]
  float* A    = sm1;
  float* dinv = sm1 + NN * SM;
  const int g   = blockIdx.x;
  const int tid = threadIdx.x;

  for (int e = tid; e < NN * NN; e += 256) {
    int i = e >> 7, j = e & 127;
    A[i * SM + j] = 0.f;
  }
  __syncthreads();
  const int* s = src + (size_t)g * E;
  const int* d = dst + (size_t)g * E;
  for (int e = tid; e < E; e += 256) {
    int a = s[e], b = d[e];
    A[a * SM + b] = 1.f;     // benign races: all write 1.0
    A[b * SM + a] = 1.f;
  }
  __syncthreads();
  if (tid < NN) {
    float acc = 0.f;
    for (int j = 0; j < NN; ++j) acc += A[tid * SM + j];
    dinv[tid] = (acc > 0.f) ? (float)(1.0 / sqrt((double)acc)) : 0.f;
  }
  __syncthreads();
  float* Lg = Lout + (size_t)g * NN * NN;
  for (int e = tid; e < NN * NN; e += 256) {
    int i = e >> 7, j = e & 127;
    Lg[e] = ((i == j) ? 1.f : 0.f) - dinv[i] * dinv[j] * A[i * SM + j];
  }
}

// ---------------------------------------------------------------------------
// KPOW2 (R22): L2 = L @ L. 512 blocks. L staged f32 in LDS. 2 blocks/CU.
// ---------------------------------------------------------------------------
__global__ __launch_bounds__(512, 4) void kpow2(
    const float* __restrict__ L, double* __restrict__ L2) {
  extern __shared__ float Bs[];             // 128 x 132 f32
  const int bid = blockIdx.x;
  const int g = bid >> 3, q = bid & 7;
  const int tid = threadIdx.x;
  const int wv = tid >> 6, ln = tid & 63;
  const int m  = ln & 15, kq = ln >> 4;
  const int rb = 16 * q;                    // row-band base
  const int cb = wv;                        // column tile

  int rIdx[4], cIdx[4];
  {
    d4 z = {0.0, 0.0, 0.0, 0.0};
    d4 pr = __builtin_amdgcn_mfma_f64_16x16x4f64((double)m, 1.0, z, 0, 0, 0);
    d4 pc = __builtin_amdgcn_mfma_f64_16x16x4f64(1.0, (double)m, z, 0, 0, 0);
#pragma unroll
    for (int r = 0; r < 4; ++r) {
      rIdx[r] = ((int)(pr[r] * 0.25 + 0.5)) & 15;
      cIdx[r] = ((int)(pc[r] * 0.25 + 0.5)) & 15;
    }
  }

  const float* Lg = L + (size_t)g * NN * NN;
  for (int e4 = tid; e4 < (NN * NN) / 4; e4 += 512) {
    int i = e4 >> 5, j4 = (e4 & 31) * 4;
    *(float4*)(Bs + i * SF + j4) = *(const float4*)(Lg + i * NN + j4);
  }
  __syncthreads();

  d4 acc = {0.0, 0.0, 0.0, 0.0};
  for (int kc = 0; kc < 32; ++kc) {
    double a = (double)Bs[(rb + m) * SF + 4 * kc + kq];
    double b = (double)Bs[(4 * kc + kq) * SF + 16 * cb + m];
    acc = __builtin_amdgcn_mfma_f64_16x16x4f64(a, b, acc, 0, 0, 0);
  }
  double* out = L2 + (size_t)g * NN * NN;
#pragma unroll
  for (int r = 0; r < 4; ++r)
    out[(rb + rIdx[r]) * NN + 16 * cb + cIdx[r]] = acc[r];
}

// ---------------------------------------------------------------------------
// KPOW34 (R22): 512 blocks = g(6b) x quarter(2b) x job(1b).
// ---------------------------------------------------------------------------
__global__ __launch_bounds__(512, 4) void kpow34(
    const float* __restrict__ L, const double* __restrict__ L2,
    double* __restrict__ L3, double* __restrict__ L4) {
  extern __shared__ float Bs[];             // 128 x 132 f32 (job0 only)
  const int bid = blockIdx.x;
  const int g = bid >> 3, q = (bid >> 1) & 3, job = bid & 1;
  const int tid = threadIdx.x;
  const int wv = tid >> 6, ln = tid & 63;
  const int m  = ln & 15, kq = ln >> 4;
  const int rb = 32 * q + 16 * (wv & 1);
  const int cb0 = 2 * (wv >> 1);

  int rIdx[4], cIdx[4];
  {
    d4 z = {0.0, 0.0, 0.0, 0.0};
    d4 pr = __builtin_amdgcn_mfma_f64_16x16x4f64((double)m, 1.0, z, 0, 0, 0);
    d4 pc = __builtin_amdgcn_mfma_f64_16x16x4f64(1.0, (double)m, z, 0, 0, 0);
#pragma unroll
    for (int r = 0; r < 4; ++r) {
      rIdx[r] = ((int)(pr[r] * 0.25 + 0.5)) & 15;
      cIdx[r] = ((int)(pc[r] * 0.25 + 0.5)) & 15;
    }
  }

  const float*  Lg  = L  + (size_t)g * NN * NN;
  const double* L2g = L2 + (size_t)g * NN * NN;
  if (job == 0) {
    for (int e4 = tid; e4 < (NN * NN) / 4; e4 += 512) {
      int i = e4 >> 5, j4 = (e4 & 31) * 4;
      *(float4*)(Bs + i * SF + j4) = *(const float4*)(Lg + i * NN + j4);
    }
  }
  __syncthreads();

  d4 acc[2];
#pragma unroll
  for (int c = 0; c < 2; ++c) {
    acc[c][0] = 0.0; acc[c][1] = 0.0; acc[c][2] = 0.0; acc[c][3] = 0.0;
  }
  if (job == 0) {
    for (int kc = 0; kc < 32; ++kc) {
      double a = L2g[(rb + m) * NN + 4 * kc + kq];
#pragma unroll
      for (int c = 0; c < 2; ++c) {
        double b = (double)Bs[(4 * kc + kq) * SF + 16 * (cb0 + c) + m];
        acc[c] = __builtin_amdgcn_mfma_f64_16x16x4f64(a, b, acc[c], 0, 0, 0);
      }
    }
  } else {
    for (int kc = 0; kc < 32; ++kc) {
      double a = L2g[(rb + m) * NN + 4 * kc + kq];
#pragma unroll
      for (int c = 0; c < 2; ++c) {
        double b = L2g[(4 * kc + kq) * NN + 16 * (cb0 + c) + m];
        acc[c] = __builtin_amdgcn_mfma_f64_16x16x4f64(a, b, acc[c], 0, 0, 0);
      }
    }
  }
  double* out = (job == 0 ? L3 : L4) + (size_t)g * NN * NN;
#pragma unroll
  for (int c = 0; c < 2; ++c)
#pragma unroll
    for (int r = 0; r < 4; ++r)
      out[(rb + rIdx[r]) * NN + 16 * (cb0 + c) + cIdx[r]] = acc[c][r];
}

// ---------------------------------------------------------------------------
// K2 (R14 exact, FROZEN): algebraic assembly + blocked GJ with serial-Pi.
// 268us stable; VGPR 64 + 64 AGPR = full 128 budget at (512,4).
// R18/R19/R21 restructurings ALL spilled to scratch. DO NOT MODIFY.
// ---------------------------------------------------------------------------
__global__ __launch_bounds__(512, 4) void k2_filter(
    const float* __restrict__ L, const double* __restrict__ L2,
    const double* __restrict__ L3, const double* __restrict__ L4,
    const float* __restrict__ C, int NF, float* __restrict__ W) {
  extern __shared__ char smraw[];
  double* Rp  = (double*)smraw;                      // row panel 16x132
  double* Scd = (double*)(smraw + 16 * RS * 8);      // 8 wave scratches 16x17
  double* Pv  = (double*)(smraw + 16 * RS * 8 + 8 * 16 * SS * 8); // Pi 16x17

  const int bid = blockIdx.x;
  const int g = bid / NF, f = bid % NF;
  const int tid = threadIdx.x;
  const int wv = tid >> 6, ln = tid & 63;
  const int m  = ln & 15, kq = ln >> 4;
  double* S = Scd + wv * 16 * SS;

  double csum = 0.0;
  for (int q = 0; q < NF; ++q) { double c = (double)C[q]; csum += c * c; }
  double cn = sqrt(csum); if (cn < 1e-12) cn = 1e-12;
  const double a4 = 6.25e-6;                         // (STEP/2)^4
  const double coef = 1.4142135623730951 * a4 * ((double)C[f] / cn);
  const float  bf = (float)((double)f * 0.1);
  const double bb = (double)bf;
  const double c3 = -4.0 * bb;
  const double c2 = 6.0 * bb * bb;
  const double c1 = -4.0 * bb * bb * bb;
  const double c0 = bb * bb * bb * bb + a4;

  int rIdx[4], cIdx[4];
  {
    d4 z = {0.0, 0.0, 0.0, 0.0};
    d4 pr = __builtin_amdgcn_mfma_f64_16x16x4f64((double)m, 1.0, z, 0, 0, 0);
    d4 pc = __builtin_amdgcn_mfma_f64_16x16x4f64(1.0, (double)m, z, 0, 0, 0);
#pragma unroll
    for (int r = 0; r < 4; ++r) {
      rIdx[r] = ((int)(pr[r] * 0.25 + 0.5)) & 15;
      cIdx[r] = ((int)(pc[r] * 0.25 + 0.5)) & 15;
    }
  }

  // phase A: assemble T (D-layout) from the power matrices -- pure n^2
  const float*  Lg  = L  + (size_t)g * NN * NN;
  const double* L2g = L2 + (size_t)g * NN * NN;
  const double* L3g = L3 + (size_t)g * NN * NN;
  const double* L4g = L4 + (size_t)g * NN * NN;
  d4 T[8];
#pragma unroll
  for (int cb = 0; cb < 8; ++cb)
#pragma unroll
    for (int r = 0; r < 4; ++r) {
      int i = 16 * wv + rIdx[r], j = 16 * cb + cIdx[r];
      int idx = i * NN + j;
      double v = L4g[idx];
      v = fma(c3, L3g[idx], v);
      v = fma(c2, L2g[idx], v);
      v = fma(c1, (double)Lg[idx], v);
      if (i == j) v += c0;
      T[cb][r] = v;
    }

  // phase 4: blocked GJ, 8 steps, 3 block-barriers each, NOT unrolled
#pragma unroll 1
  for (int t = 0; t < 8; ++t) {
    if (wv == t) {
#pragma unroll
      for (int cb = 0; cb < 8; ++cb)
#pragma unroll
        for (int r = 0; r < 4; ++r)
          Rp[rIdx[r] * RS + 16 * cb + cIdx[r]] = T[cb][r];
    }
    __syncthreads();                                 // B1 (Rp visible)

    if (wv == t) {
      double sr[4];
#pragma unroll
      for (int r = 0; r < 4; ++r) sr[r] = Rp[(4 * r + kq) * RS + 16 * t + m];
#pragma unroll
      for (int k = 0; k < 16; ++k) {
        const int kr = k >> 2, kl = k & 3;
        double pv   = __shfl(sr[kr], 16 * kl + k);
        double rowv = __shfl(sr[kr], 16 * kl + m);
        double cv[4];
#pragma unroll
        for (int r = 0; r < 4; ++r) cv[r] = __shfl(sr[r], 16 * kq + k);
        double dp = 1.0 / pv;
#pragma unroll
        for (int r = 0; r < 4; ++r) {
          int i = 4 * r + kq;
          double nv;
          if (i == k)      nv = (m == k) ? dp : rowv * dp;
          else if (m == k) nv = -cv[r] * dp;
          else             nv = fma(-(cv[r] * dp), rowv, sr[r]);
          sr[r] = nv;
        }
      }
#pragma unroll
      for (int r = 0; r < 4; ++r) Pv[(4 * r + kq) * SS + m] = sr[r];
    }
    __syncthreads();                                 // B2 (Pi visible)

#pragma unroll
    for (int cb = 0; cb < 8; ++cb) {
      if (cb != t) continue;
      if (wv == t) {
#pragma unroll
        for (int r = 0; r < 4; ++r) T[cb][r] = Pv[rIdx[r] * SS + cIdx[r]];
      } else {
#pragma unroll
        for (int r = 0; r < 4; ++r) S[rIdx[r] * SS + cIdx[r]] = T[cb][r];
        __builtin_amdgcn_wave_barrier();
        d4 ncv = {0.0, 0.0, 0.0, 0.0};
#pragma unroll
        for (int kc = 0; kc < 4; ++kc) {
          double a = S[m * SS + 4 * kc + kq];
          double b = -Pv[(4 * kc + kq) * SS + m];
          ncv = __builtin_amdgcn_mfma_f64_16x16x4f64(a, b, ncv, 0, 0, 0);
        }
        T[cb] = ncv;
        __builtin_amdgcn_wave_barrier();
#pragma unroll
        for (int r = 0; r < 4; ++r) S[rIdx[r] * SS + cIdx[r]] = T[cb][r];
      }
    }
    __builtin_amdgcn_wave_barrier();

    const double* asrc = (wv == t) ? Pv : S;
#pragma unroll
    for (int cb = 0; cb < 8; ++cb) {
      if (cb == t) continue;
      d4 acc;
      if (wv == t) { acc[0] = 0.0; acc[1] = 0.0; acc[2] = 0.0; acc[3] = 0.0; }
      else         { acc = T[cb]; }
#pragma unroll
      for (int kc = 0; kc < 4; ++kc) {
        double a = asrc[m * SS + 4 * kc + kq];
        double b = Rp[(4 * kc + kq) * RS + 16 * cb + m];
        acc = __builtin_amdgcn_mfma_f64_16x16x4f64(a, b, acc, 0, 0, 0);
      }
      T[cb] = acc;
    }
    __syncthreads();                                 // B3 (Rp/Pv reads done)
  }

  // phase 5: W += coef * K^{-1}
  float* Wg = W + (size_t)g * NN * NN;
#pragma unroll
  for (int cb = 0; cb < 8; ++cb)
#pragma unroll
    for (int r = 0; r < 4; ++r)
      atomicAdd(&Wg[(16 * wv + rIdx[r]) * NN + 16 * cb + cIdx[r]],
                (float)(coef * T[cb][r]));
}

// ---------------------------------------------------------------------------
// KZ (R30): Zp[slot] = partial X @ X^T over 2x64 depth. EXACT clone of the
// measured-good k3 GEMM2 access pattern (R26): thread (tr=tid>>4, tc=tid&15)
// owns 4 rows x 8 cols; per dl: a = 4-addr broadcast b128, b = 16-addr
// 2-way-free b128 (stride 132). X chunk staged TRANSPOSED [64][132] once
// (8-way write conflict but only 16 iters/sub -- R23 lesson: staging doesn't
// matter, the x64 compute loop does). Grid 64 x NSLOT(=9), 4 blocks/CU.
// R29's kz was 392us/1.3e8 conflicts from a from-scratch layout; this reuses
// the proven one. Algebra (G=(I-W)Z(I-W)^T) already validated by R29's pass.
// ---------------------------------------------------------------------------
__global__ __launch_bounds__(512, 8) void kz(
    const float* __restrict__ x, const float* __restrict__ rs,
    float* __restrict__ Zp, int F0, int R, int DTOT, int NSLOT,
    float rscale) {
  extern __shared__ float xt[];             // [64][132]
  const int bid = blockIdx.x;
  const int g = bid / NSLOT;
  const int slot = bid % NSLOT;
  const int tid = threadIdx.x, tr = tid >> 4, tc = tid & 15;
  const float* xg = x + (size_t)g * NN * F0;
  const float* rg = rs + (size_t)g * NN * R;

  float acc[4][8];
#pragma unroll
  for (int v = 0; v < 4; ++v)
#pragma unroll
    for (int u = 0; u < 8; ++u) acc[v][u] = 0.f;

#pragma unroll 1
  for (int sub = 0; sub < 2; ++sub) {
    const int d0 = (slot * 2 + sub) * 64;
    if (d0 >= DTOT) break;                  // uniform across block
    __syncthreads();                        // previous-sub reads done
    for (int e = tid; e < NN * 64; e += 512) {
      int k = e >> 6, dl = e & 63;          // dl fastest: coalesced global
      int d = d0 + dl;
      float v = 0.f;
      if (d < DTOT) v = (d < F0) ? xg[k * F0 + d] : rg[k * R + (d - F0)] * rscale;
      xt[dl * CS + k] = v;
    }
    __syncthreads();
    for (int dl = 0; dl < 64; ++dl) {
      float4 a4 = *(const float4*)(xt + dl * CS + 4 * tr);      // broadcast
      float4 ba = *(const float4*)(xt + dl * CS + 4 * tc);      // 2-way, free
      float4 bb = *(const float4*)(xt + dl * CS + 64 + 4 * tc); // 2-way, free
      float av[4] = {a4.x, a4.y, a4.z, a4.w};
      float bv[8] = {ba.x, ba.y, ba.z, ba.w, bb.x, bb.y, bb.z, bb.w};
#pragma unroll
      for (int v = 0; v < 4; ++v)
#pragma unroll
        for (int u = 0; u < 8; ++u) acc[v][u] = fmaf(av[v], bv[u], acc[v][u]);
    }
  }
  float* Zc = Zp + ((size_t)slot * 64 + g) * NN * NN;
#pragma unroll
  for (int v = 0; v < 4; ++v) {
    float4 lo = {acc[v][0], acc[v][1], acc[v][2], acc[v][3]};
    float4 hi = {acc[v][4], acc[v][5], acc[v][6], acc[v][7]};
    *(float4*)(Zc + (4 * tr + v) * NN + 4 * tc) = lo;
    *(float4*)(Zc + (4 * tr + v) * NN + 64 + 4 * tc) = hi;
  }
}

// ---------------------------------------------------------------------------
// KGRED (R25-proven): dense out = sum of NCH partials, full grid, float4.
// ---------------------------------------------------------------------------
__global__ __launch_bounds__(256) void kgred(
    const float* __restrict__ Gp, float* __restrict__ G, int NCH) {
  const size_t cstride = (size_t)64 * NN * NN;
  size_t idx = ((size_t)blockIdx.x * 256 + threadIdx.x) * 4;
  float4 s = *(const float4*)(Gp + idx);
  for (int c = 1; c < NCH; ++c) {
    float4 v = *(const float4*)(Gp + c * cstride + idx);
    s.x += v.x; s.y += v.y; s.z += v.z; s.w += v.w;
  }
  *(float4*)(G + idx) = s;
}

// ---------------------------------------------------------------------------
// KZS1 (R30): M = Z - W @ Z. 256 blocks = g x 32-row band, 2 blocks/CU.
// Z (full) staged in LDS [128][132]; W rows streamed from global as float4
// (L2-hot, 4x band redundancy = 16MB). Inner loop: broadcast w + two
// 2-way-free b128 + 8 FMA. Thread = 1 row x 8 cols (tid>>4 row-in-band,
// tid&15 col group).
// ---------------------------------------------------------------------------
__global__ __launch_bounds__(512, 4) void kzs1(
    const float* __restrict__ Z, const float* __restrict__ W,
    float* __restrict__ M) {
  extern __shared__ float zb[];             // [128][132]
  const int bid = blockIdx.x;
  const int g = bid >> 2, band = bid & 3;
  const int tid = threadIdx.x;
  const int rr = tid >> 4, tc = tid & 15;
  const int i = band * 32 + rr;
  const float* Zg = Z + (size_t)g * NN * NN;
  const float* Wg = W + (size_t)g * NN * NN;

  for (int e4 = tid; e4 < NN * 32; e4 += 512) {
    int row = e4 >> 5, c4 = (e4 & 31) * 4;
    *(float4*)(zb + row * ZS + c4) = *(const float4*)(Zg + row * NN + c4);
  }
  __syncthreads();

  float acc[8];
#pragma unroll
  for (int u = 0; u < 8; ++u) acc[u] = 0.f;
  for (int kk = 0; kk < 32; ++kk) {
    float4 w4 = *(const float4*)(Wg + i * NN + 4 * kk);
    float wv4[4] = {w4.x, w4.y, w4.z, w4.w};
#pragma unroll
    for (int s = 0; s < 4; ++s) {
      int k = 4 * kk + s;
      float4 ba = *(const float4*)(zb + k * ZS + 4 * tc);
      float4 bb = *(const float4*)(zb + k * ZS + 64 + 4 * tc);
      acc[0] = fmaf(wv4[s], ba.x, acc[0]);
      acc[1] = fmaf(wv4[s], ba.y, acc[1]);
      acc[2] = fmaf(wv4[s], ba.z, acc[2]);
      acc[3] = fmaf(wv4[s], ba.w, acc[3]);
      acc[4] = fmaf(wv4[s], bb.x, acc[4]);
      acc[5] = fmaf(wv4[s], bb.y, acc[5]);
      acc[6] = fmaf(wv4[s], bb.z, acc[6]);
      acc[7] = fmaf(wv4[s], bb.w, acc[7]);
    }
  }
  float4 za = *(const float4*)(zb + i * ZS + 4 * tc);
  float4 zc = *(const float4*)(zb + i * ZS + 64 + 4 * tc);
  float4 lo = {za.x - acc[0], za.y - acc[1], za.z - acc[2], za.w - acc[3]};
  float4 hi = {zc.x - acc[4], zc.y - acc[5], zc.z - acc[6], zc.w - acc[7]};
  float* Mg = M + (size_t)g * NN * NN;
  *(float4*)(Mg + i * NN + 4 * tc) = lo;
  *(float4*)(Mg + i * NN + 64 + 4 * tc) = hi;
}

// ---------------------------------------------------------------------------
// KZS2 (R30): G = M - M @ W. Same structure; W (full) staged in LDS,
// M rows streamed from global.
// ---------------------------------------------------------------------------
__global__ __launch_bounds__(512, 4) void kzs2(
    const float* __restrict__ M, const float* __restrict__ W,
    float* __restrict__ G) {
  extern __shared__ float wb[];             // [128][132]
  const int bid = blockIdx.x;
  const int g = bid >> 2, band = bid & 3;
  const int tid = threadIdx.x;
  const int rr = tid >> 4, tc = tid & 15;
  const int i = band * 32 + rr;
  const float* Mg = M + (size_t)g * NN * NN;
  const float* Wg = W + (size_t)g * NN * NN;

  for (int e4 = tid; e4 < NN * 32; e4 += 512) {
    int row = e4 >> 5, c4 = (e4 & 31) * 4;
    *(float4*)(wb + row * ZS + c4) = *(const float4*)(Wg + row * NN + c4);
  }
  __syncthreads();

  float acc[8];
#pragma unroll
  for (int u = 0; u < 8; ++u) acc[u] = 0.f;
  for (int kk = 0; kk < 32; ++kk) {
    float4 m4 = *(const float4*)(Mg + i * NN + 4 * kk);
    float mv4[4] = {m4.x, m4.y, m4.z, m4.w};
#pragma unroll
    for (int s = 0; s < 4; ++s) {
      int k = 4 * kk + s;
      float4 ba = *(const float4*)(wb + k * ZS + 4 * tc);
      float4 bb = *(const float4*)(wb + k * ZS + 64 + 4 * tc);
      acc[0] = fmaf(mv4[s], ba.x, acc[0]);
      acc[1] = fmaf(mv4[s], ba.y, acc[1]);
      acc[2] = fmaf(mv4[s], ba.z, acc[2]);
      acc[3] = fmaf(mv4[s], ba.w, acc[3]);
      acc[4] = fmaf(mv4[s], bb.x, acc[4]);
      acc[5] = fmaf(mv4[s], bb.y, acc[5]);
      acc[6] = fmaf(mv4[s], bb.z, acc[6]);
      acc[7] = fmaf(mv4[s], bb.w, acc[7]);
    }
  }
  float4 ma = *(const float4*)(Mg + i * NN + 4 * tc);
  float4 mc = *(const float4*)(Mg + i * NN + 64 + 4 * tc);
  float4 lo = {ma.x - acc[0], ma.y - acc[1], ma.z - acc[2], ma.w - acc[3]};
  float4 hi = {mc.x - acc[4], mc.y - acc[5], mc.z - acc[6], mc.w - acc[7]};
  float* Gg = G + (size_t)g * NN * NN;
  *(float4*)(Gg + i * NN + 4 * tc) = lo;
  *(float4*)(Gg + i * NN + 64 + 4 * tc) = hi;
}

// ---------------------------------------------------------------------------
// KEMB (R29, validated): emb_d = sum_k v_k X[k,d], v = (1 - colsum(W))/128.
// ---------------------------------------------------------------------------
__global__ __launch_bounds__(256) void kemb(
    const float* __restrict__ x, const float* __restrict__ rs,
    const float* __restrict__ W, float* __restrict__ emb,
    int F0, int R, int DTOT, float rscale) {
  __shared__ float v[NN];
  const int bid = blockIdx.x;
  const int g = bid >> 2, q = bid & 3;
  const int tid = threadIdx.x;
  const float* Wg = W + (size_t)g * NN * NN;
  if (tid < NN) {
    float s = 0.f;
    for (int i2 = 0; i2 < NN; ++i2) s += Wg[i2 * NN + tid];   // coalesced
    v[tid] = (1.f - s) * (1.f / 128.f);
  }
  __syncthreads();
  const float* xg = x + (size_t)g * NN * F0;
  const float* rg = rs + (size_t)g * NN * R;
  const int DQ = (DTOT + 3) >> 2;
  for (int dd = tid; dd < DQ; dd += 256) {
    int d = q * DQ + dd;
    if (d < DTOT) {
      float acc = 0.f;
      for (int k = 0; k < NN; ++k) {
        float xv = (d < F0) ? xg[k * F0 + d] : rg[k * R + (d - F0)] * rscale;
        acc = fmaf(v[k], xv, acc);
      }
      emb[(size_t)g * 1152 + d] = acc;
    }
  }
}

// ---------------------------------------------------------------------------
// K45 (R28): full-machine parallelism for both phases.
// Blocks 0..255 = k4 partials (4/graph, 32-row quarter; f64 atomicAdd into
// spt[g], scaling -> k5b). Blocks 256..383 = k5a cdist (2/row).
// ---------------------------------------------------------------------------
__global__ __launch_bounds__(256) void k45_fused(
    const float* __restrict__ G, double* __restrict__ spt,
    const float* __restrict__ emb, float* __restrict__ Dm, int DTOT) {
  __shared__ float inr[NN];
  __shared__ double red[4];
  const int bid = blockIdx.x, tid = threadIdx.x;
  if (bid < 256) {
    const int g = bid >> 2, qt = bid & 3;
    const float* Gg = G + (size_t)g * NN * NN;
    if (tid < NN) {
      float n = sqrtf(fmaxf(Gg[tid * NN + tid], 0.f));
      inr[tid] = 1.f / fmaxf(n, 1e-12f);
    }
    __syncthreads();
    double s = 0.0;
    const int base = qt * 4096;                 // 32-row quarter
    for (int e0 = tid; e0 < 4096; e0 += 256) {
      int e = base + e0;
      int i = e >> 7, j = e & 127;
      s += (double)(fabsf(Gg[e]) * inr[i] * inr[j]);
    }
    for (int off = 32; off; off >>= 1) s += __shfl_down(s, off);
    int wave = tid >> 6, lane = tid & 63;
    if (lane == 0) red[wave] = s;
    __syncthreads();
    if (tid == 0) atomicAdd(&spt[g], red[0] + red[1] + red[2] + red[3]);
  } else {
    const int ii = bid - 256;
    const int i = ii >> 1, h = ii & 1;          // row i, j-half h
    const int wv = tid >> 6, l = tid & 63;
    float ei[18];
#pragma unroll
    for (int s = 0; s < 18; ++s) {
      int d = l + 64 * s;
      ei[s] = (d < DTOT) ? emb[(size_t)i * 1152 + d] : 0.f;
    }
    for (int jj = 8 * h; jj < 8 * h + 8; ++jj) {
      int j = 4 * jj + wv;
      float acc = 0.f;
#pragma unroll
      for (int s = 0; s < 18; ++s) {
        int d = l + 64 * s;
        if (d < DTOT) {
          float df = ei[s] - emb[(size_t)j * 1152 + d];
          acc = fmaf(df, df, acc);
        }
      }
      for (int off = 32; off; off >>= 1) acc += __shfl_down(acc, off);
      if (l == 0) Dm[i * 64 + j] = (acc > 0.f) ? sqrtf(acc) : 0.f;
    }
  }
}

// ---------------------------------------------------------------------------
// K5b (R28): 4 waves, one class per wave; spt holds raw |.|-sum (scaled here).
// ---------------------------------------------------------------------------
__global__ __launch_bounds__(256) void k5b_final(
    const float* __restrict__ Dm, const double* __restrict__ spt,
    const float* __restrict__ C, int NF,
    const int* __restrict__ ncls, float* __restrict__ out) {
  __shared__ double redH[8];     // per-wave {hl1, hl2}
  __shared__ double redS;
  const int tid = threadIdx.x;
  const int wv = tid >> 6, lane = tid & 63;
  const int nc = ncls[0];

  double hl1 = 0.0, hl2 = 0.0;
  const double beta = 1.0 / (double)nc + 1e-13;
  for (int cc = wv; cc < nc; cc += 4) {
    bool ip = (lane % nc) == cc;
    double ps = 0.0, ns = 0.0;
    for (int j = 0; j < 64; ++j) {
      double dv = (double)Dm[lane * 64 + j];
      bool jp = (j % nc) == cc;
      if (ip && jp) ps += dv;
      if (!ip && !jp) ns += dv;
    }
    for (int off = 32; off; off >>= 1) {
      ps += __shfl_down(ps, off);
      ns += __shfl_down(ns, off);
    }
    if (lane == 0) {
      int npos = 0;
      for (int q = 0; q < 64; ++q) if (q % nc == cc) npos++;
      int nneg = 64 - npos;
      hl2 += ps / ((double)npos * (double)npos);
      hl1 += -(ns / ((double)nneg * (double)nneg)) / beta;
    }
  }
  if (lane == 0) { redH[2 * wv] = hl1; redH[2 * wv + 1] = hl2; }

  if (wv == 0) {
    double sp = -spt[lane] * (1.0 / (double)(NN * NN));   // k4 scaling
    double spf = sp * exp(-((double)(64 - lane)) * log(64.0));
    for (int off = 32; off; off >>= 1) spf += __shfl_down(spf, off);
    if (lane == 0) redS = spf;
  }
  __syncthreads();

  if (tid == 0) {
    double h1 = redH[0] + redH[2] + redH[4] + redH[6];
    double h2 = redH[1] + redH[3] + redH[5] + redH[7];
    double l1 = 0.0, l2 = 0.0;
    for (int q = 0; q < NF; ++q) { double cv = (double)C[q]; l1 += fabs(cv); l2 += cv * cv; }
    l2 = sqrt(l2); if (l2 < 1e-12) l2 = 1e-12;
    double dims = sqrt((double)NF);
    double sc = (dims - l1 / l2) / (dims - 1.0);
    out[0] = (float)(sc + h2 + h1 + redS);
  }
}

// ---------------------------------------------------------------------------
extern "C" void kernel_launch(void* const* d_in, const int* in_sizes, int n_in,
                              void* d_out, int out_size, void* d_ws, size_t ws_size,
                              hipStream_t stream) {
  (void)n_in; (void)out_size; (void)ws_size;
  const float* x    = (const float*)d_in[0];
  const float* rs   = (const float*)d_in[1];
  const float* C    = (const float*)d_in[2];
  const int*   esrc = (const int*)d_in[3];
  const int*   edst = (const int*)d_in[4];
  const int*   ncls = (const int*)d_in[5];
  float* out = (float*)d_out;

  const int F0   = in_sizes[0] / (64 * 128);
  const int R    = in_sizes[1] / (64 * 128);
  const int NF   = in_sizes[2];
  const int E    = in_sizes[3] / 64;
  const int DTOT = F0 + R;
  const int NSLOT = (DTOT + 127) / 128;   // kz slots (2x64-depth each) = 9
  const float rscale = (float)(1.0 / sqrt((double)R));

  char* ws = (char*)d_ws;
  size_t off = 0;
  float*  L    = (float*)(ws + off);  off += (size_t)64 * NN * NN * 4;   // 4MB; Z reuses after k2
  float*  W    = (float*)(ws + off);  off += (size_t)64 * NN * NN * 4;   // 4MB
  // Zp (NSLOT x 4MB = 36MB) overlays L2d/L3d/L4d (24MB, dead after k2) + ext
  float*  Zp   = (float*)(ws + off);
  double* L2d  = (double*)(ws + off); off += (size_t)64 * NN * NN * 8;   // 8MB
  double* L3d  = (double*)(ws + off); off += (size_t)64 * NN * NN * 8;   // 8MB
  double* L4d  = (double*)(ws + off); off += (size_t)64 * NN * NN * 8;   // 8MB
  {
    size_t zp_bytes = (size_t)NSLOT * 64 * NN * NN * 4;
    size_t have = (size_t)3 * 64 * NN * NN * 8;
    if (zp_bytes > have) off += zp_bytes - have;
  }
  float*  emb  = (float*)(ws + off);  off += (size_t)64 * 1152 * 4;
  double* spt  = (double*)(ws + off); off += (size_t)64 * 8;
  float*  Dm   = (float*)(ws + off);  off += (size_t)64 * 64 * 4;
  float*  Z    = L;                   // dense Z reuses L (dead after k2)
  float*  M    = Zp;                  // M reuses Zp[0] (dead after kgred)
  float*  G    = Zp + (size_t)64 * NN * NN;  // G reuses Zp[1]

  hipMemsetAsync(W, 0, (size_t)64 * NN * NN * 4, stream);
  hipMemsetAsync(spt, 0, (size_t)64 * 8, stream);   // k4 partials accumulate

  const int lds1 = (NN * SM + NN) * 4;             // 66560
  const int ldsf = NN * SF * 4;                    // 67584 (f32 staging)
  const int lds2 = 16 * RS * 8 + 8 * 16 * SS * 8 + 16 * SS * 8;  // 36480
  const int ldsz  = 64 * CS * 4;                   // 33792 (kz) -> 4/CU
  const int ldszs = NN * ZS * 4;                   // 67584 (kzs1/2) -> 2/CU
  hipFuncSetAttribute((const void*)k1_lap,    hipFuncAttributeMaxDynamicSharedMemorySize, lds1);
  hipFuncSetAttribute((const void*)kpow2,     hipFuncAttributeMaxDynamicSharedMemorySize, ldsf);
  hipFuncSetAttribute((const void*)kpow34,    hipFuncAttributeMaxDynamicSharedMemorySize, ldsf);
  hipFuncSetAttribute((const void*)k2_filter, hipFuncAttributeMaxDynamicSharedMemorySize, lds2);
  hipFuncSetAttribute((const void*)kz,        hipFuncAttributeMaxDynamicSharedMemorySize, ldsz);
  hipFuncSetAttribute((const void*)kzs1,      hipFuncAttributeMaxDynamicSharedMemorySize, ldszs);
  hipFuncSetAttribute((const void*)kzs2,      hipFuncAttributeMaxDynamicSharedMemorySize, ldszs);

  k1_lap<<<64, 256, lds1, stream>>>(esrc, edst, E, L);
  kpow2<<<512, 512, ldsf, stream>>>(L, L2d);
  kpow34<<<512, 512, ldsf, stream>>>(L, L2d, L3d, L4d);
  k2_filter<<<64 * NF, 512, lds2, stream>>>(L, L2d, L3d, L4d, C, NF, W);
  kz<<<64 * NSLOT, 512, ldsz, stream>>>(x, rs, Zp, F0, R, DTOT, NSLOT, rscale);
  kgred<<<1024, 256, 0, stream>>>(Zp, Z, NSLOT);
  kzs1<<<256, 512, ldszs, stream>>>(Z, W, M);
  kzs2<<<256, 512, ldszs, stream>>>(M, W, G);
  kemb<<<256, 256, 0, stream>>>(x, rs, W, emb, F0, R, DTOT, rscale);
  k45_fused<<<384, 256, 0, stream>>>(G, spt, emb, Dm, DTOT);
  k5b_final<<<1, 256, 0, stream>>>(Dm, spt, C, NF, ncls, out);
}

// Round 14
// 537.753 us; speedup vs baseline: 1.6942x; 1.1819x over previous
//
#include <hip/hip_runtime.h>
#include <math.h>

#define NN 128
#define SM 129   // padded LDS stride for 128-wide f32 tiles
#define TS 132   // k3-128 tile stride
#define RS 132   // row-panel stride (doubles)
#define SS 17    // per-wave scratch stride (doubles)
#define SF 132   // f32 staging stride (16B-aligned rows -> float4)
#define XS 68    // k3-64 X stride (128x68 f32 = 34.8KB)
#define YS 132   // k3-64 yT stride (64x132 f32 = 33.8KB, overlays X)

typedef double d4 __attribute__((ext_vector_type(4)));

// ---------------------------------------------------------------------------
// K1 (R17): build symmetric-normalized Laplacian per graph (f32) only.
// ---------------------------------------------------------------------------
__global__ __launch_bounds__(256) void k1_lap(
    const int* __restrict__ src, const int* __restrict__ dst,
    int E, float* __restrict__ Lout) {
  extern __shared__ float sm1[];            // A[128*129] + dinv[128]
  float* A    = sm1;
  float* dinv = sm1 + NN * SM;
  const int g   = blockIdx.x;
  const int tid = threadIdx.x;

  for (int e = tid; e < NN * NN; e += 256) {
    int i = e >> 7, j = e & 127;
    A[i * SM + j] = 0.f;
  }
  __syncthreads();
  const int* s = src + (size_t)g * E;
  const int* d = dst + (size_t)g * E;
  for (int e = tid; e < E; e += 256) {
    int a = s[e], b = d[e];
    A[a * SM + b] = 1.f;     // benign races: all write 1.0
    A[b * SM + a] = 1.f;
  }
  __syncthreads();
  if (tid < NN) {
    float acc = 0.f;
    for (int j = 0; j < NN; ++j) acc += A[tid * SM + j];
    dinv[tid] = (acc > 0.f) ? (float)(1.0 / sqrt((double)acc)) : 0.f;
  }
  __syncthreads();
  float* Lg = Lout + (size_t)g * NN * NN;
  for (int e = tid; e < NN * NN; e += 256) {
    int i = e >> 7, j = e & 127;
    Lg[e] = ((i == j) ? 1.f : 0.f) - dinv[i] * dinv[j] * A[i * SM + j];
  }
}

// ---------------------------------------------------------------------------
// KPOW2 (R22): L2 = L @ L. 512 blocks. L staged f32 in LDS. 2 blocks/CU.
// ---------------------------------------------------------------------------
__global__ __launch_bounds__(512, 4) void kpow2(
    const float* __restrict__ L, double* __restrict__ L2) {
  extern __shared__ float Bs[];             // 128 x 132 f32
  const int bid = blockIdx.x;
  const int g = bid >> 3, q = bid & 7;
  const int tid = threadIdx.x;
  const int wv = tid >> 6, ln = tid & 63;
  const int m  = ln & 15, kq = ln >> 4;
  const int rb = 16 * q;                    // row-band base
  const int cb = wv;                        // column tile

  int rIdx[4], cIdx[4];
  {
    d4 z = {0.0, 0.0, 0.0, 0.0};
    d4 pr = __builtin_amdgcn_mfma_f64_16x16x4f64((double)m, 1.0, z, 0, 0, 0);
    d4 pc = __builtin_amdgcn_mfma_f64_16x16x4f64(1.0, (double)m, z, 0, 0, 0);
#pragma unroll
    for (int r = 0; r < 4; ++r) {
      rIdx[r] = ((int)(pr[r] * 0.25 + 0.5)) & 15;
      cIdx[r] = ((int)(pc[r] * 0.25 + 0.5)) & 15;
    }
  }

  const float* Lg = L + (size_t)g * NN * NN;
  for (int e4 = tid; e4 < (NN * NN) / 4; e4 += 512) {
    int i = e4 >> 5, j4 = (e4 & 31) * 4;
    *(float4*)(Bs + i * SF + j4) = *(const float4*)(Lg + i * NN + j4);
  }
  __syncthreads();

  d4 acc = {0.0, 0.0, 0.0, 0.0};
  for (int kc = 0; kc < 32; ++kc) {
    double a = (double)Bs[(rb + m) * SF + 4 * kc + kq];
    double b = (double)Bs[(4 * kc + kq) * SF + 16 * cb + m];
    acc = __builtin_amdgcn_mfma_f64_16x16x4f64(a, b, acc, 0, 0, 0);
  }
  double* out = L2 + (size_t)g * NN * NN;
#pragma unroll
  for (int r = 0; r < 4; ++r)
    out[(rb + rIdx[r]) * NN + 16 * cb + cIdx[r]] = acc[r];
}

// ---------------------------------------------------------------------------
// KPOW34 (R22): 512 blocks = g(6b) x quarter(2b) x job(1b).
// ---------------------------------------------------------------------------
__global__ __launch_bounds__(512, 4) void kpow34(
    const float* __restrict__ L, const double* __restrict__ L2,
    double* __restrict__ L3, double* __restrict__ L4) {
  extern __shared__ float Bs[];             // 128 x 132 f32 (job0 only)
  const int bid = blockIdx.x;
  const int g = bid >> 3, q = (bid >> 1) & 3, job = bid & 1;
  const int tid = threadIdx.x;
  const int wv = tid >> 6, ln = tid & 63;
  const int m  = ln & 15, kq = ln >> 4;
  const int rb = 32 * q + 16 * (wv & 1);
  const int cb0 = 2 * (wv >> 1);

  int rIdx[4], cIdx[4];
  {
    d4 z = {0.0, 0.0, 0.0, 0.0};
    d4 pr = __builtin_amdgcn_mfma_f64_16x16x4f64((double)m, 1.0, z, 0, 0, 0);
    d4 pc = __builtin_amdgcn_mfma_f64_16x16x4f64(1.0, (double)m, z, 0, 0, 0);
#pragma unroll
    for (int r = 0; r < 4; ++r) {
      rIdx[r] = ((int)(pr[r] * 0.25 + 0.5)) & 15;
      cIdx[r] = ((int)(pc[r] * 0.25 + 0.5)) & 15;
    }
  }

  const float*  Lg  = L  + (size_t)g * NN * NN;
  const double* L2g = L2 + (size_t)g * NN * NN;
  if (job == 0) {
    for (int e4 = tid; e4 < (NN * NN) / 4; e4 += 512) {
      int i = e4 >> 5, j4 = (e4 & 31) * 4;
      *(float4*)(Bs + i * SF + j4) = *(const float4*)(Lg + i * NN + j4);
    }
  }
  __syncthreads();

  d4 acc[2];
#pragma unroll
  for (int c = 0; c < 2; ++c) {
    acc[c][0] = 0.0; acc[c][1] = 0.0; acc[c][2] = 0.0; acc[c][3] = 0.0;
  }
  if (job == 0) {
    for (int kc = 0; kc < 32; ++kc) {
      double a = L2g[(rb + m) * NN + 4 * kc + kq];
#pragma unroll
      for (int c = 0; c < 2; ++c) {
        double b = (double)Bs[(4 * kc + kq) * SF + 16 * (cb0 + c) + m];
        acc[c] = __builtin_amdgcn_mfma_f64_16x16x4f64(a, b, acc[c], 0, 0, 0);
      }
    }
  } else {
    for (int kc = 0; kc < 32; ++kc) {
      double a = L2g[(rb + m) * NN + 4 * kc + kq];
#pragma unroll
      for (int c = 0; c < 2; ++c) {
        double b = L2g[(4 * kc + kq) * NN + 16 * (cb0 + c) + m];
        acc[c] = __builtin_amdgcn_mfma_f64_16x16x4f64(a, b, acc[c], 0, 0, 0);
      }
    }
  }
  double* out = (job == 0 ? L3 : L4) + (size_t)g * NN * NN;
#pragma unroll
  for (int c = 0; c < 2; ++c)
#pragma unroll
    for (int r = 0; r < 4; ++r)
      out[(rb + rIdx[r]) * NN + 16 * (cb0 + c) + cIdx[r]] = acc[c][r];
}

// ---------------------------------------------------------------------------
// K2 (R14 exact, FROZEN): algebraic assembly + blocked GJ with serial-Pi.
// 268us stable; VGPR 64 + 64 AGPR = full 128 budget at (512,4).
// R18/R19/R21 restructurings ALL spilled to scratch. DO NOT MODIFY.
// ---------------------------------------------------------------------------
__global__ __launch_bounds__(512, 4) void k2_filter(
    const float* __restrict__ L, const double* __restrict__ L2,
    const double* __restrict__ L3, const double* __restrict__ L4,
    const float* __restrict__ C, int NF, float* __restrict__ W) {
  extern __shared__ char smraw[];
  double* Rp  = (double*)smraw;                      // row panel 16x132
  double* Scd = (double*)(smraw + 16 * RS * 8);      // 8 wave scratches 16x17
  double* Pv  = (double*)(smraw + 16 * RS * 8 + 8 * 16 * SS * 8); // Pi 16x17

  const int bid = blockIdx.x;
  const int g = bid / NF, f = bid % NF;
  const int tid = threadIdx.x;
  const int wv = tid >> 6, ln = tid & 63;
  const int m  = ln & 15, kq = ln >> 4;
  double* S = Scd + wv * 16 * SS;

  double csum = 0.0;
  for (int q = 0; q < NF; ++q) { double c = (double)C[q]; csum += c * c; }
  double cn = sqrt(csum); if (cn < 1e-12) cn = 1e-12;
  const double a4 = 6.25e-6;                         // (STEP/2)^4
  const double coef = 1.4142135623730951 * a4 * ((double)C[f] / cn);
  const float  bf = (float)((double)f * 0.1);
  const double bb = (double)bf;
  const double c3 = -4.0 * bb;
  const double c2 = 6.0 * bb * bb;
  const double c1 = -4.0 * bb * bb * bb;
  const double c0 = bb * bb * bb * bb + a4;

  int rIdx[4], cIdx[4];
  {
    d4 z = {0.0, 0.0, 0.0, 0.0};
    d4 pr = __builtin_amdgcn_mfma_f64_16x16x4f64((double)m, 1.0, z, 0, 0, 0);
    d4 pc = __builtin_amdgcn_mfma_f64_16x16x4f64(1.0, (double)m, z, 0, 0, 0);
#pragma unroll
    for (int r = 0; r < 4; ++r) {
      rIdx[r] = ((int)(pr[r] * 0.25 + 0.5)) & 15;
      cIdx[r] = ((int)(pc[r] * 0.25 + 0.5)) & 15;
    }
  }

  // phase A: assemble T (D-layout) from the power matrices -- pure n^2
  const float*  Lg  = L  + (size_t)g * NN * NN;
  const double* L2g = L2 + (size_t)g * NN * NN;
  const double* L3g = L3 + (size_t)g * NN * NN;
  const double* L4g = L4 + (size_t)g * NN * NN;
  d4 T[8];
#pragma unroll
  for (int cb = 0; cb < 8; ++cb)
#pragma unroll
    for (int r = 0; r < 4; ++r) {
      int i = 16 * wv + rIdx[r], j = 16 * cb + cIdx[r];
      int idx = i * NN + j;
      double v = L4g[idx];
      v = fma(c3, L3g[idx], v);
      v = fma(c2, L2g[idx], v);
      v = fma(c1, (double)Lg[idx], v);
      if (i == j) v += c0;
      T[cb][r] = v;
    }

  // phase 4: blocked GJ, 8 steps, 3 block-barriers each, NOT unrolled
#pragma unroll 1
  for (int t = 0; t < 8; ++t) {
    if (wv == t) {
#pragma unroll
      for (int cb = 0; cb < 8; ++cb)
#pragma unroll
        for (int r = 0; r < 4; ++r)
          Rp[rIdx[r] * RS + 16 * cb + cIdx[r]] = T[cb][r];
    }
    __syncthreads();                                 // B1 (Rp visible)

    if (wv == t) {
      double sr[4];
#pragma unroll
      for (int r = 0; r < 4; ++r) sr[r] = Rp[(4 * r + kq) * RS + 16 * t + m];
#pragma unroll
      for (int k = 0; k < 16; ++k) {
        const int kr = k >> 2, kl = k & 3;
        double pv   = __shfl(sr[kr], 16 * kl + k);
        double rowv = __shfl(sr[kr], 16 * kl + m);
        double cv[4];
#pragma unroll
        for (int r = 0; r < 4; ++r) cv[r] = __shfl(sr[r], 16 * kq + k);
        double dp = 1.0 / pv;
#pragma unroll
        for (int r = 0; r < 4; ++r) {
          int i = 4 * r + kq;
          double nv;
          if (i == k)      nv = (m == k) ? dp : rowv * dp;
          else if (m == k) nv = -cv[r] * dp;
          else             nv = fma(-(cv[r] * dp), rowv, sr[r]);
          sr[r] = nv;
        }
      }
#pragma unroll
      for (int r = 0; r < 4; ++r) Pv[(4 * r + kq) * SS + m] = sr[r];
    }
    __syncthreads();                                 // B2 (Pi visible)

#pragma unroll
    for (int cb = 0; cb < 8; ++cb) {
      if (cb != t) continue;
      if (wv == t) {
#pragma unroll
        for (int r = 0; r < 4; ++r) T[cb][r] = Pv[rIdx[r] * SS + cIdx[r]];
      } else {
#pragma unroll
        for (int r = 0; r < 4; ++r) S[rIdx[r] * SS + cIdx[r]] = T[cb][r];
        __builtin_amdgcn_wave_barrier();
        d4 ncv = {0.0, 0.0, 0.0, 0.0};
#pragma unroll
        for (int kc = 0; kc < 4; ++kc) {
          double a = S[m * SS + 4 * kc + kq];
          double b = -Pv[(4 * kc + kq) * SS + m];
          ncv = __builtin_amdgcn_mfma_f64_16x16x4f64(a, b, ncv, 0, 0, 0);
        }
        T[cb] = ncv;
        __builtin_amdgcn_wave_barrier();
#pragma unroll
        for (int r = 0; r < 4; ++r) S[rIdx[r] * SS + cIdx[r]] = T[cb][r];
      }
    }
    __builtin_amdgcn_wave_barrier();

    const double* asrc = (wv == t) ? Pv : S;
#pragma unroll
    for (int cb = 0; cb < 8; ++cb) {
      if (cb == t) continue;
      d4 acc;
      if (wv == t) { acc[0] = 0.0; acc[1] = 0.0; acc[2] = 0.0; acc[3] = 0.0; }
      else         { acc = T[cb]; }
#pragma unroll
      for (int kc = 0; kc < 4; ++kc) {
        double a = asrc[m * SS + 4 * kc + kq];
        double b = Rp[(4 * kc + kq) * RS + 16 * cb + m];
        acc = __builtin_amdgcn_mfma_f64_16x16x4f64(a, b, acc, 0, 0, 0);
      }
      T[cb] = acc;
    }
    __syncthreads();                                 // B3 (Rp/Pv reads done)
  }

  // phase 5: W += coef * K^{-1}
  float* Wg = W + (size_t)g * NN * NN;
#pragma unroll
  for (int cb = 0; cb < 8; ++cb)
#pragma unroll
    for (int r = 0; r < 4; ++r)
      atomicAdd(&Wg[(16 * wv + rIdx[r]) * NN + 16 * cb + cIdx[r]],
                (float)(coef * T[cb][r]));
}

// ---------------------------------------------------------------------------
// K3-64 (R27): 64-col chunks -> LDS 35KB -> 4 blocks/CU (32 waves, max occ).
// X [128][68] overlaid by yT [64][132] in place. k-loop b128 reads 2-way-
// free. acc[4][4] keeps regs under the 64-VGPR cap of (512,8). Atomic-free
// G partials (R24 lesson: device-scope atomics write through to HBM).
// ---------------------------------------------------------------------------
__global__ __launch_bounds__(512, 8) void k3_fused64(
    const float* __restrict__ x, const float* __restrict__ rs,
    const float* __restrict__ W, float* __restrict__ Gp,
    float* __restrict__ emb, int F0, int R, int DTOT, int NCH2,
    float rscale) {
  extern __shared__ float sm3[];
  float* ldsX = sm3;                 // [128][68] X, then [64][132] yT in place
  float* embA = sm3 + 128 * XS;      // 64 f32 emb accumulator
  const int bid = blockIdx.x;
  const int g = bid / NCH2;
  const int c = bid % NCH2;
  const int d0 = c * 64;
  const int tid = threadIdx.x, tr = tid >> 4, tc = tid & 15;

  const float* xg = x + (size_t)g * NN * F0;
  const float* rg = rs + (size_t)g * NN * R;
  for (int e = tid; e < NN * 64; e += 512) {
    int k = e >> 6, dl = e & 63;
    int d = d0 + dl;
    float v = 0.f;
    if (d < DTOT) v = (d < F0) ? xg[k * F0 + d] : rg[k * R + (d - F0)] * rscale;
    ldsX[k * XS + dl] = v;
  }
  if (tid < 64) embA[tid] = 0.f;
  __syncthreads();

  // GEMM1: y = X - W@X. Thread: rows 4tr+v, cols 4tc+u (within chunk).
  const float* Wg = W + (size_t)g * NN * NN;
  float acc[4][4];
#pragma unroll
  for (int v = 0; v < 4; ++v)
#pragma unroll
    for (int u = 0; u < 4; ++u) acc[v][u] = 0.f;
  float4 w4 = *(const float4*)(Wg + 4 * tr);
  for (int k = 0; k < NN; ++k) {
    float4 w4n;
    if (k < NN - 1) w4n = *(const float4*)(Wg + (k + 1) * NN + 4 * tr);
    float4 xa = *(const float4*)(ldsX + k * XS + 4 * tc);  // 2-way, free
    float xv[4] = {xa.x, xa.y, xa.z, xa.w};
    float wvv[4] = {w4.x, w4.y, w4.z, w4.w};
#pragma unroll
    for (int v = 0; v < 4; ++v)
#pragma unroll
      for (int u = 0; u < 4; ++u) acc[v][u] = fmaf(wvv[v], xv[u], acc[v][u]);
    w4 = w4n;
  }
  // y = X - (W@X)
#pragma unroll
  for (int v = 0; v < 4; ++v) {
    float4 sa = *(const float4*)(ldsX + (4 * tr + v) * XS + 4 * tc);
    acc[v][0] = sa.x - acc[v][0]; acc[v][1] = sa.y - acc[v][1];
    acc[v][2] = sa.z - acc[v][2]; acc[v][3] = sa.w - acc[v][3];
  }

  // emb partials: column sums via LDS atomics
#pragma unroll
  for (int u = 0; u < 4; ++u) {
    float s = acc[0][u] + acc[1][u] + acc[2][u] + acc[3][u];
    atomicAdd(&embA[4 * tc + u], s);
  }
  __syncthreads();                 // all X reads + embA adds complete

  // yT [64][132] in place over the dead X buffer (once per block)
#pragma unroll
  for (int v = 0; v < 4; ++v)
#pragma unroll
    for (int u = 0; u < 4; ++u)
      ldsX[(4 * tc + u) * YS + 4 * tr + v] = acc[v][u];
  __syncthreads();

  if (tid < 64) {
    int d = d0 + tid;
    if (d < DTOT) emb[(size_t)g * 1152 + d] = embA[tid] * (1.f / 128.f);
  }

  // GEMM2: G[i][j] += sum_{d in chunk} y[i,d]*y[j,d]; depth 64.
  float gg[4][8];
#pragma unroll
  for (int v = 0; v < 4; ++v)
#pragma unroll
    for (int u = 0; u < 8; ++u) gg[v][u] = 0.f;
  for (int dl = 0; dl < 64; ++dl) {
    float4 a4v = *(const float4*)(ldsX + dl * YS + 4 * tr);      // broadcast
    float4 ba  = *(const float4*)(ldsX + dl * YS + 4 * tc);      // 2-way
    float4 bb  = *(const float4*)(ldsX + dl * YS + 64 + 4 * tc); // 2-way
    float bv[8] = {ba.x, ba.y, ba.z, ba.w, bb.x, bb.y, bb.z, bb.w};
    float av[4] = {a4v.x, a4v.y, a4v.z, a4v.w};
#pragma unroll
    for (int v = 0; v < 4; ++v)
#pragma unroll
      for (int u = 0; u < 8; ++u) gg[v][u] = fmaf(av[v], bv[u], gg[v][u]);
  }
  float* Gc = Gp + ((size_t)c * 64 + g) * NN * NN;
#pragma unroll
  for (int v = 0; v < 4; ++v) {
    float4 lo = {gg[v][0], gg[v][1], gg[v][2], gg[v][3]};
    float4 hi = {gg[v][4], gg[v][5], gg[v][6], gg[v][7]};
    *(float4*)(Gc + (4 * tr + v) * NN + 4 * tc) = lo;
    *(float4*)(Gc + (4 * tr + v) * NN + 64 + 4 * tc) = hi;
  }
}

// ---------------------------------------------------------------------------
// KGRED (R25): dense G = sum_c Gp[c] on a FULL grid (1024 blocks, float4).
// ---------------------------------------------------------------------------
__global__ __launch_bounds__(256) void kgred(
    const float* __restrict__ Gp, float* __restrict__ G, int NCH) {
  const size_t cstride = (size_t)64 * NN * NN;
  size_t idx = ((size_t)blockIdx.x * 256 + threadIdx.x) * 4;
  float4 s = *(const float4*)(Gp + idx);
  for (int c = 1; c < NCH; ++c) {
    float4 v = *(const float4*)(Gp + c * cstride + idx);
    s.x += v.x; s.y += v.y; s.z += v.z; s.w += v.w;
  }
  *(float4*)(G + idx) = s;
}

// ---------------------------------------------------------------------------
// K45 (R28): full-machine parallelism for both phases.
// Blocks 0..255 = k4 partials (4/graph, 32-row quarter; f64 atomicAdd into
// spt[g], scaling -> k5b). Blocks 256..383 = k5a cdist (2/row).
// ---------------------------------------------------------------------------
__global__ __launch_bounds__(256) void k45_fused(
    const float* __restrict__ G, double* __restrict__ spt,
    const float* __restrict__ emb, float* __restrict__ Dm, int DTOT) {
  __shared__ float inr[NN];
  __shared__ double red[4];
  const int bid = blockIdx.x, tid = threadIdx.x;
  if (bid < 256) {
    const int g = bid >> 2, qt = bid & 3;
    const float* Gg = G + (size_t)g * NN * NN;
    if (tid < NN) {
      float n = sqrtf(fmaxf(Gg[tid * NN + tid], 0.f));
      inr[tid] = 1.f / fmaxf(n, 1e-12f);
    }
    __syncthreads();
    double s = 0.0;
    const int base = qt * 4096;                 // 32-row quarter
    for (int e0 = tid; e0 < 4096; e0 += 256) {
      int e = base + e0;
      int i = e >> 7, j = e & 127;
      s += (double)(fabsf(Gg[e]) * inr[i] * inr[j]);
    }
    for (int off = 32; off; off >>= 1) s += __shfl_down(s, off);
    int wave = tid >> 6, lane = tid & 63;
    if (lane == 0) red[wave] = s;
    __syncthreads();
    if (tid == 0) atomicAdd(&spt[g], red[0] + red[1] + red[2] + red[3]);
  } else {
    const int ii = bid - 256;
    const int i = ii >> 1, h = ii & 1;          // row i, j-half h
    const int wv = tid >> 6, l = tid & 63;
    float ei[18];
#pragma unroll
    for (int s = 0; s < 18; ++s) {
      int d = l + 64 * s;
      ei[s] = (d < DTOT) ? emb[(size_t)i * 1152 + d] : 0.f;
    }
    for (int jj = 8 * h; jj < 8 * h + 8; ++jj) {
      int j = 4 * jj + wv;
      float acc = 0.f;
#pragma unroll
      for (int s = 0; s < 18; ++s) {
        int d = l + 64 * s;
        if (d < DTOT) {
          float df = ei[s] - emb[(size_t)j * 1152 + d];
          acc = fmaf(df, df, acc);
        }
      }
      for (int off = 32; off; off >>= 1) acc += __shfl_down(acc, off);
      if (l == 0) Dm[i * 64 + j] = (acc > 0.f) ? sqrtf(acc) : 0.f;
    }
  }
}

// ---------------------------------------------------------------------------
// K5b (R28): 4 waves, one class per wave; spt holds raw |.|-sum (scaled here).
// ---------------------------------------------------------------------------
__global__ __launch_bounds__(256) void k5b_final(
    const float* __restrict__ Dm, const double* __restrict__ spt,
    const float* __restrict__ C, int NF,
    const int* __restrict__ ncls, float* __restrict__ out) {
  __shared__ double redH[8];     // per-wave {hl1, hl2}
  __shared__ double redS;
  const int tid = threadIdx.x;
  const int wv = tid >> 6, lane = tid & 63;
  const int nc = ncls[0];

  double hl1 = 0.0, hl2 = 0.0;
  const double beta = 1.0 / (double)nc + 1e-13;
  for (int cc = wv; cc < nc; cc += 4) {
    bool ip = (lane % nc) == cc;
    double ps = 0.0, ns = 0.0;
    for (int j = 0; j < 64; ++j) {
      double dv = (double)Dm[lane * 64 + j];
      bool jp = (j % nc) == cc;
      if (ip && jp) ps += dv;
      if (!ip && !jp) ns += dv;
    }
    for (int off = 32; off; off >>= 1) {
      ps += __shfl_down(ps, off);
      ns += __shfl_down(ns, off);
    }
    if (lane == 0) {
      int npos = 0;
      for (int q = 0; q < 64; ++q) if (q % nc == cc) npos++;
      int nneg = 64 - npos;
      hl2 += ps / ((double)npos * (double)npos);
      hl1 += -(ns / ((double)nneg * (double)nneg)) / beta;
    }
  }
  if (lane == 0) { redH[2 * wv] = hl1; redH[2 * wv + 1] = hl2; }

  if (wv == 0) {
    double sp = -spt[lane] * (1.0 / (double)(NN * NN));   // k4 scaling
    double spf = sp * exp(-((double)(64 - lane)) * log(64.0));
    for (int off = 32; off; off >>= 1) spf += __shfl_down(spf, off);
    if (lane == 0) redS = spf;
  }
  __syncthreads();

  if (tid == 0) {
    double h1 = redH[0] + redH[2] + redH[4] + redH[6];
    double h2 = redH[1] + redH[3] + redH[5] + redH[7];
    double l1 = 0.0, l2 = 0.0;
    for (int q = 0; q < NF; ++q) { double cv = (double)C[q]; l1 += fabs(cv); l2 += cv * cv; }
    l2 = sqrt(l2); if (l2 < 1e-12) l2 = 1e-12;
    double dims = sqrt((double)NF);
    double sc = (dims - l1 / l2) / (dims - 1.0);
    out[0] = (float)(sc + h2 + h1 + redS);
  }
}

// ---------------------------------------------------------------------------
extern "C" void kernel_launch(void* const* d_in, const int* in_sizes, int n_in,
                              void* d_out, int out_size, void* d_ws, size_t ws_size,
                              hipStream_t stream) {
  (void)n_in; (void)out_size;
  const float* x    = (const float*)d_in[0];
  const float* rs   = (const float*)d_in[1];
  const float* C    = (const float*)d_in[2];
  const int*   esrc = (const int*)d_in[3];
  const int*   edst = (const int*)d_in[4];
  const int*   ncls = (const int*)d_in[5];
  float* out = (float*)d_out;

  const int F0   = in_sizes[0] / (64 * 128);
  const int R    = in_sizes[1] / (64 * 128);
  const int NF   = in_sizes[2];
  const int E    = in_sizes[3] / 64;
  const int DTOT = F0 + R;
  const int NCH  = (DTOT + 127) / 128;   // 128-col chunks (not used; kept)
  const int NCH2 = (DTOT + 63) / 64;     // 64-col chunks
  const float rscale = (float)(1.0 / sqrt((double)R));
  (void)NCH;

  char* ws = (char*)d_ws;
  size_t off = 0;
  float*  L    = (float*)(ws + off);  off += (size_t)64 * NN * NN * 4;   // 4MB; reused as dense G
  float*  W    = (float*)(ws + off);  off += (size_t)64 * NN * NN * 4;   // 4MB
  // Gp (NCH2 x 4MB = 72MB) overlays L2d/L3d/L4d (24MB, dead after k2) + ext
  float*  Gp   = (float*)(ws + off);
  double* L2d  = (double*)(ws + off); off += (size_t)64 * NN * NN * 8;   // 8MB
  double* L3d  = (double*)(ws + off); off += (size_t)64 * NN * NN * 8;   // 8MB
  double* L4d  = (double*)(ws + off); off += (size_t)64 * NN * NN * 8;   // 8MB
  {
    size_t gp_bytes = (size_t)NCH2 * 64 * NN * NN * 4;
    size_t have = (size_t)3 * 64 * NN * NN * 8;
    if (gp_bytes > have) off += gp_bytes - have;
  }
  float*  emb  = (float*)(ws + off);  off += (size_t)64 * 1152 * 4;
  double* spt  = (double*)(ws + off); off += (size_t)64 * 8;
  float*  Dm   = (float*)(ws + off);  off += (size_t)64 * 64 * 4;
  float*  G    = L;                   // dense G reuses L (dead after k2)

  hipMemsetAsync(W, 0, (size_t)64 * NN * NN * 4, stream);
  hipMemsetAsync(spt, 0, (size_t)64 * 8, stream);   // k4 partials accumulate

  const int lds1 = (NN * SM + NN) * 4;             // 66560
  const int ldsf = NN * SF * 4;                    // 67584 (f32 staging)
  const int lds2 = 16 * RS * 8 + 8 * 16 * SS * 8 + 16 * SS * 8;  // 36480
  const int lds364 = (128 * XS + 64) * 4;          // 35072 (k3-64) -> 4/CU
  hipFuncSetAttribute((const void*)k1_lap,    hipFuncAttributeMaxDynamicSharedMemorySize, lds1);
  hipFuncSetAttribute((const void*)kpow2,     hipFuncAttributeMaxDynamicSharedMemorySize, ldsf);
  hipFuncSetAttribute((const void*)kpow34,    hipFuncAttributeMaxDynamicSharedMemorySize, ldsf);
  hipFuncSetAttribute((const void*)k2_filter, hipFuncAttributeMaxDynamicSharedMemorySize, lds2);
  hipFuncSetAttribute((const void*)k3_fused64, hipFuncAttributeMaxDynamicSharedMemorySize, lds364);

  k1_lap<<<64, 256, lds1, stream>>>(esrc, edst, E, L);
  kpow2<<<512, 512, ldsf, stream>>>(L, L2d);
  kpow34<<<512, 512, ldsf, stream>>>(L, L2d, L3d, L4d);
  k2_filter<<<64 * NF, 512, lds2, stream>>>(L, L2d, L3d, L4d, C, NF, W);
  k3_fused64<<<64 * NCH2, 512, lds364, stream>>>(x, rs, W, Gp, emb, F0, R, DTOT, NCH2, rscale);
  kgred<<<1024, 256, 0, stream>>>(Gp, G, NCH2);
  k45_fused<<<384, 256, 0, stream>>>(G, spt, emb, Dm, DTOT);
  k5b_final<<<1, 256, 0, stream>>>(Dm, spt, C, NF, ncls, out);
}